// Round 5
// baseline (436.438 us; speedup 1.0000x reference)
//
#include <hip/hip_runtime.h>
#include <hip/hip_fp16.h>

#define NN 100000
#define NE 3200000
#define FIN 512
#define HIDN 64
#define NC 16
#define LEAKY 0.2f
#define LG 0.2f

#define NBLK 391  // ceil(100000/256)

// MFMA MLP params
#define GM 64         // rows per block (4 waves x 16 rows)
#define HLD2 68       // H row stride in LDS (floats)
#define MLP_BLKS 1563 // ceil(100000/64)

// bucket sort params
#define BSH 9                 // 512 nodes per bucket
#define NBUCK 196             // ceil(100000/512)
#define TILE_A 2048

typedef float4 f4;
typedef short bf16x8 __attribute__((ext_vector_type(8)));
typedef float f32x4 __attribute__((ext_vector_type(4)));

// 8x f32 -> bf16x8 via v_cvt_pk_bf16_f32 (RNE, 1 op per 2 floats)
__device__ __forceinline__ bf16x8 cvt8(const f4 a, const f4 b) {
  union { unsigned u[4]; bf16x8 v; } o;
  asm("v_cvt_pk_bf16_f32 %0, %1, %2" : "=v"(o.u[0]) : "v"(a.x), "v"(a.y));
  asm("v_cvt_pk_bf16_f32 %0, %1, %2" : "=v"(o.u[1]) : "v"(a.z), "v"(a.w));
  asm("v_cvt_pk_bf16_f32 %0, %1, %2" : "=v"(o.u[2]) : "v"(b.x), "v"(b.y));
  asm("v_cvt_pk_bf16_f32 %0, %1, %2" : "=v"(o.u[3]) : "v"(b.z), "v"(b.w));
  return o.v;
}

// ---------------- prep: W0 (512x64) -> W0^T hi/lo bf16 ([64][512]) ----------------
__global__ __launch_bounds__(256) void k_w0t(const float* __restrict__ W0,
    short* __restrict__ Wh, short* __restrict__ Wl) {
  const int i = blockIdx.x*256 + threadIdx.x;   // i = c*512 + k
  if (i >= HIDN*FIN) return;
  const int c = i >> 9, k = i & 511;
  const float w = W0[(size_t)k*HIDN + c];
  const unsigned b = __float_as_uint(w);
  const short hi = (short)(b >> 16);
  const float hif = __uint_as_float(b & 0xffff0000u);
  const short lo = (short)(__float_as_uint(w - hif) >> 16);
  Wh[i] = hi; Wl[i] = lo;
}

// ---------------- MLP: Z = relu(X@W0)@W1 via bf16-X x (hi+lo)-W MFMA ----------------
// GM=64: 1563 blocks -> ~6 blocks/CU; small VGPR footprint -> 6 waves/SIMD (TLP
// hides the per-iter W L2 latency that 3 waves/SIMD could not).
__global__ __launch_bounds__(256, 6) void k_mlp2(
    const float* __restrict__ X, const short* __restrict__ W0Th,
    const short* __restrict__ W0Tl, const float* __restrict__ W1,
    const float* __restrict__ a1v, const float* __restrict__ a2v,
    float* __restrict__ Z, float* __restrict__ f1o, float* __restrict__ f2o)
{
  __shared__ float Hs[GM][HLD2];
  __shared__ float W1s[HIDN*NC];
  const int t = threadIdx.x;
  const int wid = t >> 6, lane = t & 63;
  const int r = lane & 15, g = lane >> 4;   // g = k-group 0..3
  const int rowbase = blockIdx.x*GM + wid*16;
  int row0 = rowbase + r;  if (row0 >= NN) row0 = NN-1;
  const float* pa0 = X + (size_t)row0*FIN + g*8;
  const short* pbh = W0Th + (size_t)r*FIN + g*8;
  const short* pbl = W0Tl + (size_t)r*FIN + g*8;

  *(f4*)(W1s + t*4) = *(const f4*)(W1 + t*4);

  f32x4 acc[4];
  #pragma unroll
  for (int n=0;n<4;++n) acc[n] = (f32x4){0.f,0.f,0.f,0.f};

  // X staging: 2 ping-pong stages, depth-2 prefetch, fully unrolled k-loop
  f4 xs[2][2];   // [stage][half]
  xs[0][0] = *(const f4*)(pa0);      xs[0][1] = *(const f4*)(pa0+4);
  xs[1][0] = *(const f4*)(pa0+32);   xs[1][1] = *(const f4*)(pa0+36);

  #pragma unroll
  for (int ks=0; ks<16; ++ks) {
    const int st = ks & 1;          // compile-time after unroll
    const int koff = ks*32;
    // W loads for this iter (L2-resident; issued first)
    bf16x8 bh[4], bl[4];
    #pragma unroll
    for (int n=0;n<4;++n) {
      bh[n] = *(const bf16x8*)(pbh + (size_t)n*16*FIN + koff);
      bl[n] = *(const bf16x8*)(pbl + (size_t)n*16*FIN + koff);
    }
    // convert current X (arrived: issued 2 iters ago)
    const bf16x8 xb0 = cvt8(xs[st][0], xs[st][1]);
    // prefetch X for ks+2 into the freed stage
    if (ks + 2 < 16) {
      const int ko2 = koff + 64;
      xs[st][0] = *(const f4*)(pa0+ko2);  xs[st][1] = *(const f4*)(pa0+ko2+4);
    }
    #pragma unroll
    for (int n=0;n<4;++n) {
      acc[n] = __builtin_amdgcn_mfma_f32_16x16x32_bf16(xb0, bh[n], acc[n], 0,0,0);
      acc[n] = __builtin_amdgcn_mfma_f32_16x16x32_bf16(xb0, bl[n], acc[n], 0,0,0);
    }
  }

  // C layout (m89): col = lane&15, row = 4*(lane>>4)+reg -> H tile to LDS (relu, fp32)
  {
    const int hr = wid*16 + g*4;
    #pragma unroll
    for (int n=0;n<4;++n)
      #pragma unroll
      for (int q=0;q<4;++q)
        Hs[hr+q][n*16+r] = fmaxf(acc[n][q], 0.f);
  }
  __syncthreads();

  // layer 2: Z = H @ W1 (fp32), plus f1/f2
  if (t < GM) {
    const int node = blockIdx.x*GM + t;
    if (node < NN) {
      float z[16];
      #pragma unroll
      for (int c=0;c<16;++c) z[c]=0.f;
      #pragma unroll 4
      for (int h=0; h<HIDN; ++h) {
        const float hv = Hs[t][h];
        const f4* wp = (const f4*)(W1s + h*NC);
        const f4 w0_=wp[0], w1_=wp[1], w2_=wp[2], w3_=wp[3];
        z[0]+=hv*w0_.x; z[1]+=hv*w0_.y; z[2]+=hv*w0_.z; z[3]+=hv*w0_.w;
        z[4]+=hv*w1_.x; z[5]+=hv*w1_.y; z[6]+=hv*w1_.z; z[7]+=hv*w1_.w;
        z[8]+=hv*w2_.x; z[9]+=hv*w2_.y; z[10]+=hv*w2_.z; z[11]+=hv*w2_.w;
        z[12]+=hv*w3_.x; z[13]+=hv*w3_.y; z[14]+=hv*w3_.z; z[15]+=hv*w3_.w;
      }
      f4* zp = (f4*)(Z + (size_t)node*NC);
      zp[0] = make_float4(z[0],z[1],z[2],z[3]);
      zp[1] = make_float4(z[4],z[5],z[6],z[7]);
      zp[2] = make_float4(z[8],z[9],z[10],z[11]);
      zp[3] = make_float4(z[12],z[13],z[14],z[15]);
      float s1=0.f, s2=0.f;
      #pragma unroll
      for (int c=0;c<16;++c) { s1 += z[c]*a1v[c]; s2 += z[c]*a2v[c]; }
      f1o[node]=s1; f2o[node]=s2;
    }
  }
}

// ---------------- CSR build: bucket histogram ----------------
__global__ __launch_bounds__(256) void k_bhist(const int* __restrict__ src,
                                               int* __restrict__ bcnt) {
  __shared__ int c[256];
  const int t = threadIdx.x;
  c[t] = 0;
  __syncthreads();
  int i = blockIdx.x*256 + t;
  const int stride = gridDim.x*256;
  for (; i < NE; i += stride) atomicAdd(&c[src[i] >> BSH], 1);
  __syncthreads();
  if (t < NBUCK && c[t]) atomicAdd(&bcnt[t], c[t]);
}

__global__ __launch_bounds__(256) void k_bscan(const int* __restrict__ bcnt,
    int* __restrict__ bbase, int* __restrict__ gcur) {
  __shared__ int s[256];
  const int t = threadIdx.x;
  const int v = (t < NBUCK) ? bcnt[t] : 0;
  s[t] = v;
  __syncthreads();
  for (int off=1; off<256; off<<=1) {
    const int x = (t>=off) ? s[t-off] : 0;
    __syncthreads();
    s[t] += x;
    __syncthreads();
  }
  if (t < NBUCK) { bbase[t] = s[t]-v; gcur[t] = s[t]-v; }
}

// ---------------- CSR build phase A: LDS multi-split into 196 buckets ----------------
__global__ __launch_bounds__(256) void k_binA(const int* __restrict__ src,
    const int* __restrict__ dst, const float* __restrict__ gcn,
    int* __restrict__ gcur, int2* __restrict__ tmp)
{
  __shared__ int cnt[256];
  __shared__ int scn[256];
  __shared__ int cur[256];
  __shared__ int gbase[256];
  __shared__ int2 stage[TILE_A];
  __shared__ unsigned char sb[TILE_A];
  const int t = threadIdx.x;
  const int e0 = blockIdx.x*TILE_A;
  const int ecount = min(TILE_A, NE - e0);
  cnt[t] = 0;
  __syncthreads();
  int w0v[8], w1v[8], bv[8];
  #pragma unroll
  for (int it=0; it<8; ++it) {
    const int i = e0 + it*256 + t;
    bv[it] = -1;
    if (i < NE) {
      const int s_ = src[i];
      const int b = s_ >> BSH;
      bv[it] = b;
      w0v[it] = dst[i] | ((s_ & ((1<<BSH)-1)) << 17);
      w1v[it] = __float_as_int(gcn[i]);
      atomicAdd(&cnt[b], 1);
    }
  }
  __syncthreads();
  scn[t] = cnt[t];
  __syncthreads();
  for (int off=1; off<256; off<<=1) {
    const int x = (t>=off) ? scn[t-off] : 0;
    __syncthreads();
    scn[t] += x;
    __syncthreads();
  }
  cur[t] = scn[t] - cnt[t];                 // local exclusive prefix
  if (cnt[t] > 0) gbase[t] = atomicAdd(&gcur[t], cnt[t]);
  __syncthreads();
  #pragma unroll
  for (int it=0; it<8; ++it) {
    if (bv[it] >= 0) {
      const int pos = atomicAdd(&cur[bv[it]], 1);
      stage[pos] = make_int2(w0v[it], w1v[it]);
      sb[pos] = (unsigned char)bv[it];
    }
  }
  __syncthreads();
  // flush: LDS is bucket-sorted; global writes are contiguous runs per bucket
  #pragma unroll
  for (int it=0; it<8; ++it) {
    const int slot = it*256 + t;
    if (slot < ecount) {
      const int b = sb[slot];
      const int gd = gbase[b] + slot - (scn[b] - cnt[b]);
      tmp[gd] = stage[slot];
    }
  }
}

// ---------------- CSR build phase B: per-bucket fine sort (L2-resident writes) ----------------
__global__ __launch_bounds__(512) void k_binB(const int* __restrict__ bbase,
    const int* __restrict__ bcnt, const int2* __restrict__ tmp,
    int* __restrict__ rowptr, int* __restrict__ col, float* __restrict__ val)
{
  __shared__ int cnt[512];
  __shared__ int scn[512];
  __shared__ int cur[512];
  const int t = threadIdx.x;
  const int b = blockIdx.x;
  const int node0 = b << BSH;
  const int base = bbase[b];
  const int n = bcnt[b];
  cnt[t] = 0;
  __syncthreads();
  for (int i = t; i < n; i += 512)
    atomicAdd(&cnt[tmp[base+i].x >> 17], 1);
  __syncthreads();
  scn[t] = cnt[t];
  __syncthreads();
  for (int off=1; off<512; off<<=1) {
    const int x = (t>=off) ? scn[t-off] : 0;
    __syncthreads();
    scn[t] += x;
    __syncthreads();
  }
  const int excl = scn[t] - cnt[t];
  cur[t] = excl;
  if (node0 + t < NN) rowptr[node0 + t] = base + excl;
  if (b == 0 && t == 0) rowptr[NN] = NE;
  __syncthreads();
  for (int i = t; i < n; i += 512) {
    const int2 e = tmp[base+i];
    const int ls = e.x >> 17;
    const int p = base + atomicAdd(&cur[ls], 1);
    col[p] = e.x & 0x1FFFF;
    val[p] = __int_as_float(e.y);
  }
}

// ---------------- sparse attention hop: half-wave (32 lanes) per row ----------------
__global__ __launch_bounds__(256) void k_hop(const int* __restrict__ rowptr,
    const int* __restrict__ col, const float* __restrict__ val,
    const float* __restrict__ Zin, const float* __restrict__ f1in,
    const float* __restrict__ f2in, float* __restrict__ Zout,
    float* __restrict__ f1out, float* __restrict__ f2out,
    const float* __restrict__ a1v, const float* __restrict__ a2v, int writeF)
{
  const int t = threadIdx.x;
  const int lane = t & 31;
  const int row = blockIdx.x*8 + (t>>5);
  if (row >= NN) return;
  const int start = rowptr[row], end = rowptr[row+1];
  f4* zo = (f4*)(Zout + (size_t)row*NC);
  if (end == start) {
    if (lane == 0) {
      const f4 zz = make_float4(0.f,0.f,0.f,0.f);
      zo[0]=zz; zo[1]=zz; zo[2]=zz; zo[3]=zz;
      if (writeF) { f1out[row]=0.f; f2out[row]=0.f; }
    }
    return;
  }
  const float f1r = f1in[row];
  const int nit = (end - start + 31) >> 5;
  float ev[2]; int cv[2];
  ev[0]=ev[1]=-1e30f; cv[0]=cv[1]=0;
  float m = -1e30f;
  for (int it=0; it<nit; ++it) {
    const int idx = start + it*32 + lane;
    float e = -1e30f; int cc = 0;
    if (idx < end) {
      cc = col[idx];
      const float x = f1r + f2in[cc];
      e = (x > 0.f) ? x : LEAKY*x;
    }
    if (it < 2) { ev[it] = e; cv[it] = cc; }
    m = fmaxf(m, e);
  }
  #pragma unroll
  for (int msk=1; msk<32; msk<<=1) m = fmaxf(m, __shfl_xor(m, msk));

  float s = 0.f;
  for (int it=0; it<nit; ++it) {
    const int idx = start + it*32 + lane;
    if (idx < end) {
      float e;
      if (it < 2) e = ev[it];
      else { const int cc = col[idx]; const float x = f1r + f2in[cc]; e = (x>0.f)?x:LEAKY*x; }
      s += __expf(e - m);
    }
  }
  #pragma unroll
  for (int msk=1; msk<32; msk<<=1) s += __shfl_xor(s, msk);
  const float lg_inv_s = LG / s;

  float a[16];
  #pragma unroll
  for (int c=0;c<16;++c) a[c]=0.f;
  for (int it=0; it<nit; ++it) {
    const int idx = start + it*32 + lane;
    if (idx < end) {
      int cc; float e;
      if (it < 2) { cc = cv[it]; e = ev[it]; }
      else { cc = col[idx]; const float x = f1r + f2in[cc]; e = (x>0.f)?x:LEAKY*x; }
      const float coef = (1.f-LG)*val[idx] + __expf(e - m)*lg_inv_s;
      const f4* zp = (const f4*)(Zin + (size_t)cc*NC);
      const f4 z0=zp[0], z1=zp[1], z2=zp[2], z3=zp[3];
      a[0]+=coef*z0.x; a[1]+=coef*z0.y; a[2]+=coef*z0.z; a[3]+=coef*z0.w;
      a[4]+=coef*z1.x; a[5]+=coef*z1.y; a[6]+=coef*z1.z; a[7]+=coef*z1.w;
      a[8]+=coef*z2.x; a[9]+=coef*z2.y; a[10]+=coef*z2.z; a[11]+=coef*z2.w;
      a[12]+=coef*z3.x; a[13]+=coef*z3.y; a[14]+=coef*z3.z; a[15]+=coef*z3.w;
    }
  }
  #pragma unroll
  for (int msk=1; msk<32; msk<<=1) {
    #pragma unroll
    for (int c=0;c<16;++c) a[c] += __shfl_xor(a[c], msk);
  }
  if (lane == 0) {
    zo[0] = make_float4(a[0],a[1],a[2],a[3]);
    zo[1] = make_float4(a[4],a[5],a[6],a[7]);
    zo[2] = make_float4(a[8],a[9],a[10],a[11]);
    zo[3] = make_float4(a[12],a[13],a[14],a[15]);
    if (writeF) {
      float s1=0.f, s2=0.f;
      #pragma unroll
      for (int c=0;c<16;++c) { s1 += a[c]*a1v[c]; s2 += a[c]*a2v[c]; }
      f1out[row]=s1; f2out[row]=s2;
    }
  }
}

// ---------------- final per-node hop-attention mix ----------------
__global__ void k_mix(const float* __restrict__ Z0, const float* __restrict__ Z1,
                      const float* __restrict__ Z2, const float* __restrict__ Wat,
                      float* __restrict__ out) {
  const int n = blockIdx.x*blockDim.x + threadIdx.x;
  if (n >= NN) return;
  const f4* p0 = (const f4*)(Z0 + (size_t)n*NC);
  const f4* p1 = (const f4*)(Z1 + (size_t)n*NC);
  const f4* p2 = (const f4*)(Z2 + (size_t)n*NC);
  const f4* wp = (const f4*)(Wat + (size_t)n*NC);
  f4 a0[4], a1_[4], a2_[4], w[4];
  float t0=0.f, t1=0.f, t2=0.f;
  #pragma unroll
  for (int q=0;q<4;++q) {
    a0[q]=p0[q]; a1_[q]=p1[q]; a2_[q]=p2[q]; w[q]=wp[q];
    t0 += a0[q].x*w[q].x + a0[q].y*w[q].y + a0[q].z*w[q].z + a0[q].w*w[q].w;
    t1 += a1_[q].x*w[q].x + a1_[q].y*w[q].y + a1_[q].z*w[q].z + a1_[q].w*w[q].w;
    t2 += a2_[q].x*w[q].x + a2_[q].y*w[q].y + a2_[q].z*w[q].z + a2_[q].w*w[q].w;
  }
  const float mm = fmaxf(t0, fmaxf(t1, t2));
  const float e0 = __expf(t0-mm), e1 = __expf(t1-mm), e2 = __expf(t2-mm);
  const float inv = 1.f / (e0+e1+e2);
  const float c0 = e0*inv, c1 = e1*inv, c2 = e2*inv;
  f4* op = (f4*)(out + (size_t)n*NC);
  #pragma unroll
  for (int q=0;q<4;++q) {
    f4 r;
    r.x = c0*a0[q].x + c1*a1_[q].x + c2*a2_[q].x;
    r.y = c0*a0[q].y + c1*a1_[q].y + c2*a2_[q].y;
    r.z = c0*a0[q].z + c1*a1_[q].z + c2*a2_[q].z;
    r.w = c0*a0[q].w + c1*a1_[q].w + c2*a2_[q].w;
    op[q] = r;
  }
}

extern "C" void kernel_launch(void* const* d_in, const int* in_sizes, int n_in,
                              void* d_out, int out_size, void* d_ws, size_t ws_size,
                              hipStream_t stream) {
  const float* X   = (const float*)d_in[0];
  const float* W0  = (const float*)d_in[1];
  const float* W1  = (const float*)d_in[2];
  const float* a1  = (const float*)d_in[3];
  const float* a2  = (const float*)d_in[4];
  const float* Wat = (const float*)d_in[5];
  const float* gcn = (const float*)d_in[6];
  const int*   ei  = (const int*)d_in[7];
  const int* src = ei;
  const int* dst = ei + NE;
  float* out = (float*)d_out;

  // workspace layout (element offsets; all segment sizes are multiples of 4 elems -> 16B aligned)
  float* Z0   = (float*)d_ws;              // NN*NC
  float* fA1  = Z0 + (size_t)NN*NC;        // NN
  float* fA2  = fA1 + NN;                  // NN
  int* rowptr = (int*)(fA2 + NN);          // NN+4
  int* bcnt   = rowptr + (NN + 4);         // 256
  int* bbase  = bcnt + 256;                // 256
  int* gcur   = bbase + 256;               // 256
  short* W0Th = (short*)(gcur + 256);      // 64*512 shorts
  short* W0Tl = W0Th + HIDN*FIN;           // 64*512 shorts
  int* col    = (int*)(W0Tl + HIDN*FIN);   // NE
  float* val  = (float*)(col + NE);        // NE
  int2* tmp   = (int2*)(val + NE);         // NE int2 (dead after k_binB)
  // alias hop outputs into tmp (written only after k_binB has consumed tmp)
  float* Z1  = (float*)tmp;                // NN*NC
  float* Z2  = Z1 + (size_t)NN*NC;         // NN*NC
  float* fB1 = Z2 + (size_t)NN*NC;         // NN
  float* fB2 = fB1 + NN;                   // NN

  hipMemsetAsync(bcnt, 0, 256*sizeof(int), stream);

  k_w0t<<<(HIDN*FIN + 255)/256, 256, 0, stream>>>(W0, W0Th, W0Tl);
  k_mlp2<<<MLP_BLKS, 256, 0, stream>>>(X, W0Th, W0Tl, W1, a1, a2, Z0, fA1, fA2);
  k_bhist<<<1024, 256, 0, stream>>>(src, bcnt);
  k_bscan<<<1, 256, 0, stream>>>(bcnt, bbase, gcur);
  k_binA<<<(NE + TILE_A - 1)/TILE_A, 256, 0, stream>>>(src, dst, gcn, gcur, tmp);
  k_binB<<<NBUCK, 512, 0, stream>>>(bbase, bcnt, tmp, rowptr, col, val);
  k_hop<<<12500, 256, 0, stream>>>(rowptr, col, val, Z0, fA1, fA2, Z1, fB1, fB2, a1, a2, 1);
  k_hop<<<12500, 256, 0, stream>>>(rowptr, col, val, Z1, fB1, fB2, Z2, fB1, fB2, a1, a2, 0);
  k_mix<<<NBLK, 256, 0, stream>>>(Z0, Z1, Z2, Wat, out);
}

// Round 6
// 343.211 us; speedup vs baseline: 1.2716x; 1.2716x over previous
//
#include <hip/hip_runtime.h>
#include <hip/hip_fp16.h>

#define NN 100000
#define NE 3200000
#define FIN 512
#define HIDN 64
#define NC 16
#define LEAKY 0.2f
#define LG 0.2f

#define NBLK 391  // ceil(100000/256)

// MFMA MLP params
#define GM 64         // rows per block (4 waves x 16 rows)
#define HLD2 68       // H row stride in LDS (bf16 shorts)
#define MLP_BLKS 1563 // ceil(100000/64)

// bucket sort params
#define BSH 9                 // 512 nodes per bucket
#define NBUCK 196             // ceil(100000/512)
#define TILE_A 2048

typedef float4 f4;
typedef short bf16x8 __attribute__((ext_vector_type(8)));
typedef float f32x4 __attribute__((ext_vector_type(4)));

// 8x f32 -> bf16x8 via v_cvt_pk_bf16_f32 (RNE, 1 op per 2 floats)
__device__ __forceinline__ bf16x8 cvt8(const f4 a, const f4 b) {
  union { unsigned u[4]; bf16x8 v; } o;
  asm("v_cvt_pk_bf16_f32 %0, %1, %2" : "=v"(o.u[0]) : "v"(a.x), "v"(a.y));
  asm("v_cvt_pk_bf16_f32 %0, %1, %2" : "=v"(o.u[1]) : "v"(a.z), "v"(a.w));
  asm("v_cvt_pk_bf16_f32 %0, %1, %2" : "=v"(o.u[2]) : "v"(b.x), "v"(b.y));
  asm("v_cvt_pk_bf16_f32 %0, %1, %2" : "=v"(o.u[3]) : "v"(b.z), "v"(b.w));
  return o.v;
}

__device__ __forceinline__ float bf16f(short s) {
  return __uint_as_float(((unsigned)(unsigned short)s) << 16);
}

// ---------------- prep: W0 (512x64) fp32 -> W0^T bf16 (RNE) [64][512] ----------------
__global__ __launch_bounds__(256) void k_w0t(const float* __restrict__ W0,
                                             short* __restrict__ W0T) {
  const int i = blockIdx.x*256 + threadIdx.x;   // i = c*512 + k
  if (i >= HIDN*FIN) return;
  const int c = i >> 9, k = i & 511;
  const unsigned u = __float_as_uint(W0[(size_t)k*HIDN + c]);
  W0T[i] = (short)((u + 0x7fffu + ((u >> 16) & 1u)) >> 16);   // RNE to bf16
}

// ---------------- MLP: Z = relu(X@W0)@W1 ; W in LDS (lgkmcnt), X global (vmcnt) ----------------
__global__ __launch_bounds__(256, 2) void k_mlp3(
    const float* __restrict__ X, const short* __restrict__ W0T,
    const float* __restrict__ W1, const float* __restrict__ a1v,
    const float* __restrict__ a2v, float* __restrict__ Z,
    float* __restrict__ f1o, float* __restrict__ f2o)
{
  __shared__ __align__(16) short Wb[HIDN*FIN];   // 64 KB, XOR-swizzled bf16 W^T
  __shared__ short HsB[GM][HLD2];                // 8.5 KB bf16 H
  __shared__ float W1s[HIDN*NC];                 // 4 KB
  const int t = threadIdx.x;
  const int wid = t >> 6, lane = t & 63;
  const int r = lane & 15, g = lane >> 4;        // r: row-in-frag, g: k-group 0..3
  const int rowbase = blockIdx.x*GM + wid*16;
  int row0 = rowbase + r;  if (row0 >= NN) row0 = NN-1;
  const float* pa0 = X + (size_t)row0*FIN + g*8;

  // X prefetch: depth-4 register ping-pong (only vmcnt user in the loop)
  f4 xs[4][2];
  #pragma unroll
  for (int d=0; d<4; ++d) {
    xs[d][0] = *(const f4*)(pa0 + d*32);
    xs[d][1] = *(const f4*)(pa0 + d*32 + 4);
  }

  // stage W^T bf16 -> LDS with XOR swizzle (write and read use same map)
  #pragma unroll
  for (int i2 = 0; i2 < 16; ++i2) {
    const int i = t + i2*256;          // 0..4095 chunks of 16B
    const int row = i >> 6;            // hidden row 0..63
    const int cb = (i & 63) << 4;      // byte offset within row
    const bf16x8 v = *(const bf16x8*)(W0T + (size_t)row*FIN + (i & 63)*8);
    *(bf16x8*)((char*)Wb + row*1024 + (cb ^ ((row & 7) << 4))) = v;
  }
  *(f4*)(W1s + t*4) = *(const f4*)(W1 + t*4);
  __syncthreads();

  f32x4 acc[4];
  #pragma unroll
  for (int n=0;n<4;++n) acc[n] = (f32x4){0.f,0.f,0.f,0.f};

  #pragma unroll
  for (int ks=0; ks<16; ++ks) {
    const int st = ks & 3;             // compile-time after unroll
    // W fragments from LDS (conflict-free via swizzle; waits on lgkmcnt only)
    bf16x8 bh[4];
    #pragma unroll
    for (int n=0;n<4;++n) {
      const int wrow = n*16 + r;
      const int boff = wrow*1024 + ((ks*64 + g*16) ^ ((wrow & 7) << 4));
      bh[n] = *(const bf16x8*)((const char*)Wb + boff);
    }
    const bf16x8 xb0 = cvt8(xs[st][0], xs[st][1]);
    if (ks + 4 < 16) {                 // refill stage for iter ks+4
      xs[st][0] = *(const f4*)(pa0 + (ks+4)*32);
      xs[st][1] = *(const f4*)(pa0 + (ks+4)*32 + 4);
    }
    #pragma unroll
    for (int n=0;n<4;++n)
      acc[n] = __builtin_amdgcn_mfma_f32_16x16x32_bf16(xb0, bh[n], acc[n], 0,0,0);
  }

  // C layout (m89): col=lane&15, row=4*(lane>>4)+q -> H (relu, bf16) to LDS
  {
    const int hr = wid*16 + g*4;
    #pragma unroll
    for (int n=0;n<4;++n)
      #pragma unroll
      for (int q=0;q<4;++q) {
        const unsigned u = __float_as_uint(fmaxf(acc[n][q], 0.f));
        HsB[hr+q][n*16+r] = (short)((u + 0x7fffu + ((u >> 16) & 1u)) >> 16);
      }
  }
  __syncthreads();

  // layer 2: all 256 threads; node = wid*16+r, col-group = g (4 cols each)
  {
    const int en = wid*16 + r;
    const int node = blockIdx.x*GM + en;
    if (node < NN) {
      float z0=0.f, z1=0.f, z2=0.f, z3=0.f;
      #pragma unroll 8
      for (int h=0; h<HIDN; ++h) {
        const float hv = bf16f(HsB[en][h]);
        const f4 w = *(const f4*)(W1s + h*NC + g*4);
        z0 += hv*w.x; z1 += hv*w.y; z2 += hv*w.z; z3 += hv*w.w;
      }
      *(f4*)(Z + (size_t)node*NC + g*4) = make_float4(z0,z1,z2,z3);
      float s1 = z0*a1v[g*4+0] + z1*a1v[g*4+1] + z2*a1v[g*4+2] + z3*a1v[g*4+3];
      float s2 = z0*a2v[g*4+0] + z1*a2v[g*4+1] + z2*a2v[g*4+2] + z3*a2v[g*4+3];
      s1 += __shfl_xor(s1, 16); s1 += __shfl_xor(s1, 32);
      s2 += __shfl_xor(s2, 16); s2 += __shfl_xor(s2, 32);
      if (g == 0) { f1o[node] = s1; f2o[node] = s2; }
    }
  }
}

// ---------------- CSR build: bucket histogram ----------------
__global__ __launch_bounds__(256) void k_bhist(const int* __restrict__ src,
                                               int* __restrict__ bcnt) {
  __shared__ int c[256];
  const int t = threadIdx.x;
  c[t] = 0;
  __syncthreads();
  int i = blockIdx.x*256 + t;
  const int stride = gridDim.x*256;
  for (; i < NE; i += stride) atomicAdd(&c[src[i] >> BSH], 1);
  __syncthreads();
  if (t < NBUCK && c[t]) atomicAdd(&bcnt[t], c[t]);
}

__global__ __launch_bounds__(256) void k_bscan(const int* __restrict__ bcnt,
    int* __restrict__ bbase, int* __restrict__ gcur) {
  __shared__ int s[256];
  const int t = threadIdx.x;
  const int v = (t < NBUCK) ? bcnt[t] : 0;
  s[t] = v;
  __syncthreads();
  for (int off=1; off<256; off<<=1) {
    const int x = (t>=off) ? s[t-off] : 0;
    __syncthreads();
    s[t] += x;
    __syncthreads();
  }
  if (t < NBUCK) { bbase[t] = s[t]-v; gcur[t] = s[t]-v; }
}

// ---------------- CSR build phase A: LDS multi-split into 196 buckets ----------------
__global__ __launch_bounds__(256) void k_binA(const int* __restrict__ src,
    const int* __restrict__ dst, const float* __restrict__ gcn,
    int* __restrict__ gcur, int2* __restrict__ tmp)
{
  __shared__ int cnt[256];
  __shared__ int scn[256];
  __shared__ int cur[256];
  __shared__ int gbase[256];
  __shared__ int2 stage[TILE_A];
  __shared__ unsigned char sb[TILE_A];
  const int t = threadIdx.x;
  const int e0 = blockIdx.x*TILE_A;
  const int ecount = min(TILE_A, NE - e0);
  cnt[t] = 0;
  __syncthreads();
  int w0v[8], w1v[8], bv[8];
  #pragma unroll
  for (int it=0; it<8; ++it) {
    const int i = e0 + it*256 + t;
    bv[it] = -1;
    if (i < NE) {
      const int s_ = src[i];
      const int b = s_ >> BSH;
      bv[it] = b;
      w0v[it] = dst[i] | ((s_ & ((1<<BSH)-1)) << 17);
      w1v[it] = __float_as_int(gcn[i]);
      atomicAdd(&cnt[b], 1);
    }
  }
  __syncthreads();
  scn[t] = cnt[t];
  __syncthreads();
  for (int off=1; off<256; off<<=1) {
    const int x = (t>=off) ? scn[t-off] : 0;
    __syncthreads();
    scn[t] += x;
    __syncthreads();
  }
  cur[t] = scn[t] - cnt[t];                 // local exclusive prefix
  if (cnt[t] > 0) gbase[t] = atomicAdd(&gcur[t], cnt[t]);
  __syncthreads();
  #pragma unroll
  for (int it=0; it<8; ++it) {
    if (bv[it] >= 0) {
      const int pos = atomicAdd(&cur[bv[it]], 1);
      stage[pos] = make_int2(w0v[it], w1v[it]);
      sb[pos] = (unsigned char)bv[it];
    }
  }
  __syncthreads();
  // flush: LDS is bucket-sorted; global writes are contiguous runs per bucket
  #pragma unroll
  for (int it=0; it<8; ++it) {
    const int slot = it*256 + t;
    if (slot < ecount) {
      const int b = sb[slot];
      const int gd = gbase[b] + slot - (scn[b] - cnt[b]);
      tmp[gd] = stage[slot];
    }
  }
}

// ---------------- CSR build phase B: per-bucket fine sort (L2-resident writes) ----------------
__global__ __launch_bounds__(512) void k_binB(const int* __restrict__ bbase,
    const int* __restrict__ bcnt, const int2* __restrict__ tmp,
    int* __restrict__ rowptr, int* __restrict__ col, float* __restrict__ val)
{
  __shared__ int cnt[512];
  __shared__ int scn[512];
  __shared__ int cur[512];
  const int t = threadIdx.x;
  const int b = blockIdx.x;
  const int node0 = b << BSH;
  const int base = bbase[b];
  const int n = bcnt[b];
  cnt[t] = 0;
  __syncthreads();
  for (int i = t; i < n; i += 512)
    atomicAdd(&cnt[tmp[base+i].x >> 17], 1);
  __syncthreads();
  scn[t] = cnt[t];
  __syncthreads();
  for (int off=1; off<512; off<<=1) {
    const int x = (t>=off) ? scn[t-off] : 0;
    __syncthreads();
    scn[t] += x;
    __syncthreads();
  }
  const int excl = scn[t] - cnt[t];
  cur[t] = excl;
  if (node0 + t < NN) rowptr[node0 + t] = base + excl;
  if (b == 0 && t == 0) rowptr[NN] = NE;
  __syncthreads();
  for (int i = t; i < n; i += 512) {
    const int2 e = tmp[base+i];
    const int ls = e.x >> 17;
    const int p = base + atomicAdd(&cur[ls], 1);
    col[p] = e.x & 0x1FFFF;
    val[p] = __int_as_float(e.y);
  }
}

// ---------------- sparse attention hop: half-wave (32 lanes) per row ----------------
__global__ __launch_bounds__(256) void k_hop(const int* __restrict__ rowptr,
    const int* __restrict__ col, const float* __restrict__ val,
    const float* __restrict__ Zin, const float* __restrict__ f1in,
    const float* __restrict__ f2in, float* __restrict__ Zout,
    float* __restrict__ f1out, float* __restrict__ f2out,
    const float* __restrict__ a1v, const float* __restrict__ a2v, int writeF)
{
  const int t = threadIdx.x;
  const int lane = t & 31;
  const int row = blockIdx.x*8 + (t>>5);
  if (row >= NN) return;
  const int start = rowptr[row], end = rowptr[row+1];
  f4* zo = (f4*)(Zout + (size_t)row*NC);
  if (end == start) {
    if (lane == 0) {
      const f4 zz = make_float4(0.f,0.f,0.f,0.f);
      zo[0]=zz; zo[1]=zz; zo[2]=zz; zo[3]=zz;
      if (writeF) { f1out[row]=0.f; f2out[row]=0.f; }
    }
    return;
  }
  const float f1r = f1in[row];
  const int nit = (end - start + 31) >> 5;
  float ev[2]; int cv[2];
  ev[0]=ev[1]=-1e30f; cv[0]=cv[1]=0;
  float m = -1e30f;
  for (int it=0; it<nit; ++it) {
    const int idx = start + it*32 + lane;
    float e = -1e30f; int cc = 0;
    if (idx < end) {
      cc = col[idx];
      const float x = f1r + f2in[cc];
      e = (x > 0.f) ? x : LEAKY*x;
    }
    if (it < 2) { ev[it] = e; cv[it] = cc; }
    m = fmaxf(m, e);
  }
  #pragma unroll
  for (int msk=1; msk<32; msk<<=1) m = fmaxf(m, __shfl_xor(m, msk));

  float s = 0.f;
  for (int it=0; it<nit; ++it) {
    const int idx = start + it*32 + lane;
    if (idx < end) {
      float e;
      if (it < 2) e = ev[it];
      else { const int cc = col[idx]; const float x = f1r + f2in[cc]; e = (x>0.f)?x:LEAKY*x; }
      s += __expf(e - m);
    }
  }
  #pragma unroll
  for (int msk=1; msk<32; msk<<=1) s += __shfl_xor(s, msk);
  const float lg_inv_s = LG / s;

  float a[16];
  #pragma unroll
  for (int c=0;c<16;++c) a[c]=0.f;
  for (int it=0; it<nit; ++it) {
    const int idx = start + it*32 + lane;
    if (idx < end) {
      int cc; float e;
      if (it < 2) { cc = cv[it]; e = ev[it]; }
      else { cc = col[idx]; const float x = f1r + f2in[cc]; e = (x>0.f)?x:LEAKY*x; }
      const float coef = (1.f-LG)*val[idx] + __expf(e - m)*lg_inv_s;
      const f4* zp = (const f4*)(Zin + (size_t)cc*NC);
      const f4 z0=zp[0], z1=zp[1], z2=zp[2], z3=zp[3];
      a[0]+=coef*z0.x; a[1]+=coef*z0.y; a[2]+=coef*z0.z; a[3]+=coef*z0.w;
      a[4]+=coef*z1.x; a[5]+=coef*z1.y; a[6]+=coef*z1.z; a[7]+=coef*z1.w;
      a[8]+=coef*z2.x; a[9]+=coef*z2.y; a[10]+=coef*z2.z; a[11]+=coef*z2.w;
      a[12]+=coef*z3.x; a[13]+=coef*z3.y; a[14]+=coef*z3.z; a[15]+=coef*z3.w;
    }
  }
  #pragma unroll
  for (int msk=1; msk<32; msk<<=1) {
    #pragma unroll
    for (int c=0;c<16;++c) a[c] += __shfl_xor(a[c], msk);
  }
  if (lane == 0) {
    zo[0] = make_float4(a[0],a[1],a[2],a[3]);
    zo[1] = make_float4(a[4],a[5],a[6],a[7]);
    zo[2] = make_float4(a[8],a[9],a[10],a[11]);
    zo[3] = make_float4(a[12],a[13],a[14],a[15]);
    if (writeF) {
      float s1=0.f, s2=0.f;
      #pragma unroll
      for (int c=0;c<16;++c) { s1 += a[c]*a1v[c]; s2 += a[c]*a2v[c]; }
      f1out[row]=s1; f2out[row]=s2;
    }
  }
}

// ---------------- final per-node hop-attention mix ----------------
__global__ void k_mix(const float* __restrict__ Z0, const float* __restrict__ Z1,
                      const float* __restrict__ Z2, const float* __restrict__ Wat,
                      float* __restrict__ out) {
  const int n = blockIdx.x*blockDim.x + threadIdx.x;
  if (n >= NN) return;
  const f4* p0 = (const f4*)(Z0 + (size_t)n*NC);
  const f4* p1 = (const f4*)(Z1 + (size_t)n*NC);
  const f4* p2 = (const f4*)(Z2 + (size_t)n*NC);
  const f4* wp = (const f4*)(Wat + (size_t)n*NC);
  f4 a0[4], a1_[4], a2_[4], w[4];
  float t0=0.f, t1=0.f, t2=0.f;
  #pragma unroll
  for (int q=0;q<4;++q) {
    a0[q]=p0[q]; a1_[q]=p1[q]; a2_[q]=p2[q]; w[q]=wp[q];
    t0 += a0[q].x*w[q].x + a0[q].y*w[q].y + a0[q].z*w[q].z + a0[q].w*w[q].w;
    t1 += a1_[q].x*w[q].x + a1_[q].y*w[q].y + a1_[q].z*w[q].z + a1_[q].w*w[q].w;
    t2 += a2_[q].x*w[q].x + a2_[q].y*w[q].y + a2_[q].z*w[q].z + a2_[q].w*w[q].w;
  }
  const float mm = fmaxf(t0, fmaxf(t1, t2));
  const float e0 = __expf(t0-mm), e1 = __expf(t1-mm), e2 = __expf(t2-mm);
  const float inv = 1.f / (e0+e1+e2);
  const float c0 = e0*inv, c1 = e1*inv, c2 = e2*inv;
  f4* op = (f4*)(out + (size_t)n*NC);
  #pragma unroll
  for (int q=0;q<4;++q) {
    f4 r;
    r.x = c0*a0[q].x + c1*a1_[q].x + c2*a2_[q].x;
    r.y = c0*a0[q].y + c1*a1_[q].y + c2*a2_[q].y;
    r.z = c0*a0[q].z + c1*a1_[q].z + c2*a2_[q].z;
    r.w = c0*a0[q].w + c1*a1_[q].w + c2*a2_[q].w;
    op[q] = r;
  }
}

extern "C" void kernel_launch(void* const* d_in, const int* in_sizes, int n_in,
                              void* d_out, int out_size, void* d_ws, size_t ws_size,
                              hipStream_t stream) {
  const float* X   = (const float*)d_in[0];
  const float* W0  = (const float*)d_in[1];
  const float* W1  = (const float*)d_in[2];
  const float* a1  = (const float*)d_in[3];
  const float* a2  = (const float*)d_in[4];
  const float* Wat = (const float*)d_in[5];
  const float* gcn = (const float*)d_in[6];
  const int*   ei  = (const int*)d_in[7];
  const int* src = ei;
  const int* dst = ei + NE;
  float* out = (float*)d_out;

  // workspace layout (element offsets; all segment sizes are multiples of 4 elems -> 16B aligned)
  float* Z0   = (float*)d_ws;              // NN*NC
  float* fA1  = Z0 + (size_t)NN*NC;        // NN
  float* fA2  = fA1 + NN;                  // NN
  int* rowptr = (int*)(fA2 + NN);          // NN+4
  int* bcnt   = rowptr + (NN + 4);         // 256
  int* bbase  = bcnt + 256;                // 256
  int* gcur   = bbase + 256;               // 256
  short* W0T  = (short*)(gcur + 256);      // 64*512 shorts (bf16 RNE)
  int* col    = (int*)(W0T + HIDN*FIN);    // NE
  float* val  = (float*)(col + NE);        // NE
  int2* tmp   = (int2*)(val + NE);         // NE int2 (dead after k_binB)
  // alias hop outputs into tmp (written only after k_binB has consumed tmp)
  float* Z1  = (float*)tmp;                // NN*NC
  float* Z2  = Z1 + (size_t)NN*NC;         // NN*NC
  float* fB1 = Z2 + (size_t)NN*NC;         // NN
  float* fB2 = fB1 + NN;                   // NN

  hipMemsetAsync(bcnt, 0, 256*sizeof(int), stream);

  k_w0t<<<(HIDN*FIN + 255)/256, 256, 0, stream>>>(W0, W0T);
  k_mlp3<<<MLP_BLKS, 256, 0, stream>>>(X, W0T, W1, a1, a2, Z0, fA1, fA2);
  k_bhist<<<1024, 256, 0, stream>>>(src, bcnt);
  k_bscan<<<1, 256, 0, stream>>>(bcnt, bbase, gcur);
  k_binA<<<(NE + TILE_A - 1)/TILE_A, 256, 0, stream>>>(src, dst, gcn, gcur, tmp);
  k_binB<<<NBUCK, 512, 0, stream>>>(bbase, bcnt, tmp, rowptr, col, val);
  k_hop<<<12500, 256, 0, stream>>>(rowptr, col, val, Z0, fA1, fA2, Z1, fB1, fB2, a1, a2, 1);
  k_hop<<<12500, 256, 0, stream>>>(rowptr, col, val, Z1, fB1, fB2, Z2, fB1, fB2, a1, a2, 0);
  k_mix<<<NBLK, 256, 0, stream>>>(Z0, Z1, Z2, Wat, out);
}